// Round 8
// baseline (3891.377 us; speedup 1.0000x reference)
//
#include <hip/hip_runtime.h>

#define NB 256
#define NO 32
#define NEE 32
#define NT 16
#define NPAIR 496
#define THREADS 1024

typedef const float* fp;

struct Params {
  fp z;
  fp ee1w, ee1b, ee2w, ee2b, ee3w, ee3b;
  fp ne1w, ne1b, ne2w, ne2b, ne3w, ne3b, ne4w, ne4b;
  fp le1w, le1b, le2w, le2b, le3w, le3b;
  fp lt1w, lt1b, lt2w, lt2b, lt3w, lt3b, lt4w, lt4b, lt5w, lt5b;
  float* out;
  int tf;
};

__device__ __forceinline__ float frelu(float x) { return x > 0.f ? x : 0.f; }

// 2-row fused dense layer (node MLPs): o[r] += sum_k x_r[k] * W[k*ldw].
// x_r are LDS rows read uniformly (broadcast); W streamed from global (L1-hot),
// one weight load serves both rows.
template<int KC>
__device__ __forceinline__ void dense2(const float* x0, const float* x1,
                                       const float* W, int ldw, float o[2]) {
  float a0 = o[0], a1 = 0.f, b0 = o[1], b1 = 0.f;
#pragma unroll
  for (int kc = 0; kc < KC; ++kc) {
    float w0 = W[(4 * kc + 0) * ldw];
    float w1 = W[(4 * kc + 1) * ldw];
    float w2 = W[(4 * kc + 2) * ldw];
    float w3 = W[(4 * kc + 3) * ldw];
    float4 xa = *(const float4*)(x0 + 4 * kc);
    float4 xb = *(const float4*)(x1 + 4 * kc);
    a0 = fmaf(xa.x, w0, a0); a1 = fmaf(xa.y, w1, a1);
    a0 = fmaf(xa.z, w2, a0); a1 = fmaf(xa.w, w3, a1);
    b0 = fmaf(xb.x, w0, b0); b1 = fmaf(xb.y, w1, b1);
    b0 = fmaf(xb.z, w2, b0); b1 = fmaf(xb.w, w3, b1);
  }
  o[0] = a0 + a1; o[1] = b0 + b1;
}

// Edge MLP over this wave's 31 pairs; W2/W3 in LDS (transposed + xor-swizzled
// in float4 units -> ds_read_b128, 2 lanes/bank = conflict-free); H bounced
// through the wave's private sH slot (uniform broadcast reads).
#define PAIR_PHASE(B1, B2, B3)                                                  \
  do {                                                                          \
    for (int r_ = 0; r_ < 31; ++r_) {                                           \
      int p_ = sP[wave * 31 + r_];                                              \
      int i_ = p_ >> 8, j_ = p_ & 255;                                          \
      float h1_ = frelu(sU[i_ * 64 + lane] + sV[j_ * 64 + lane] + (B1));        \
      sHw[lane] = h1_;                                                          \
      float a0_ = (B2), a1_ = 0.f, a2_ = 0.f, a3_ = 0.f;                        \
      _Pragma("unroll")                                                         \
      for (int kc = 0; kc < 16; ++kc) {                                         \
        float4 h = *(const float4*)(sHw + 4 * kc);                              \
        float4 w = *(const float4*)(sW2 + (lane << 6) + ((kc ^ swm) << 2));     \
        a0_ = fmaf(h.x, w.x, a0_); a1_ = fmaf(h.y, w.y, a1_);                   \
        a2_ = fmaf(h.z, w.z, a2_); a3_ = fmaf(h.w, w.w, a3_);                   \
      }                                                                         \
      float h2_ = frelu((a0_ + a1_) + (a2_ + a3_));                             \
      sHw[lane] = h2_;                                                          \
      float c0_ = (B3), c1_ = 0.f, c2_ = 0.f, c3_ = 0.f;                        \
      _Pragma("unroll")                                                         \
      for (int kc = 0; kc < 16; ++kc) {                                         \
        float4 h = *(const float4*)(sHw + 4 * kc);                              \
        float4 w = *(const float4*)(sW3 + (lane << 6) + ((kc ^ swm) << 2));     \
        c0_ = fmaf(h.x, w.x, c0_); c1_ = fmaf(h.y, w.y, c1_);                   \
        c2_ = fmaf(h.z, w.z, c2_); c3_ = fmaf(h.w, w.w, c3_);                   \
      }                                                                         \
      float e3_ = (c0_ + c1_) + (c2_ + c3_);                                    \
      atomicAdd(&sAgg[i_ * 64 + lane], e3_);                                    \
      atomicAdd(&sAgg[j_ * 64 + lane], -e3_);                                   \
    }                                                                           \
  } while (0)

__global__ __launch_bounds__(THREADS) void rld_kernel(Params P) {
  const int b = blockIdx.x;
  const int tid = (int)threadIdx.x;
  const int lane = tid & 63;
  const int wave = tid >> 6;
  const int cc = lane & 31;
  const int c16 = lane & 15;
  const int swm = lane & 15;

  __shared__ float sU[NO * 64];
  __shared__ float sV[NO * 64];
  __shared__ float sAgg[NO * 64];
  __shared__ float sW[8192];            // A1: sSrc staging; then W2|W3 swizzled
  __shared__ float sH[16 * 64];
  __shared__ unsigned short sP[NPAIR];
  float* sW2 = sW;
  float* sW3 = sW + 4096;
  float* sSrc = sW;
  float* sHw = sH + (wave << 6);

  // pair index table (np.triu_indices(32,1) order), packed (i<<8)|j
  for (int p = tid; p < NPAIR; p += THREADS) {
    int i = 0, rem = p;
    while (rem >= 31 - i) { rem -= 31 - i; ++i; }
    sP[p] = (unsigned short)((i << 8) | (i + 1 + rem));
  }

  const float* zb = P.z + (size_t)b * NT * NO * NEE;
  const int i0 = wave * 2, i1 = wave * 2 + 1;
  float* pN0 = sU + (i0 << 6);   // per-wave node-MLP scratch (own sU/sV rows)
  float* pN1 = sU + (i1 << 6);
  float* pM0 = sV + (i0 << 6);
  float* pM1 = sV + (i1 << 6);

  // ===== Phase A1: u = src@ee1[:512], v = src@ee1[512:], s1 = src@ne1[:512] =====
  float au[2] = {0, 0}, av[2] = {0, 0}, s1r[2] = {0, 0};
  for (int half = 0; half < 2; ++half) {
    __syncthreads();  // publishes sP on first pass; protects sSrc reuse
    for (int idx = tid; idx < NO * 256; idx += THREADS) {
      int i = idx >> 8, kk = idx & 255;
      int k = half * 256 + kk;
      int t = k >> 5, e = k & 31;
      float v = zb[(t * NO + i) * NEE + e];
      if (t > 0) v -= zb[((t - 1) * NO + i) * NEE + e];
      sSrc[i * 256 + kk] = v;
    }
    __syncthreads();
    const float* wA = P.ee1w + (half * 256) * 64 + lane;
    const float* wB = P.ee1w + (512 + half * 256) * 64 + lane;
    const float* wC = P.ne1w + (half * 256) * 64 + lane;
#pragma unroll 4
    for (int kk = 0; kk < 256; ++kk) {
      float wa = wA[kk * 64];
      float wb = wB[kk * 64];
      float wc = wC[kk * 64];
#pragma unroll
      for (int r = 0; r < 2; ++r) {
        float s = sSrc[(i0 + r) * 256 + kk];  // uniform broadcast read
        au[r]  = fmaf(s, wa, au[r]);
        av[r]  = fmaf(s, wb, av[r]);
        s1r[r] = fmaf(s, wc, s1r[r]);
      }
    }
  }
  __syncthreads();  // all sSrc reads done before sU/sV writes and sW staging

  sU[(i0 << 6) + lane] = au[0];
  sU[(i1 << 6) + lane] = au[1];
  sV[(i0 << 6) + lane] = av[0];
  sV[(i1 << 6) + lane] = av[1];
  sAgg[(i0 << 6) + lane] = 0.f;
  sAgg[(i1 << 6) + lane] = 0.f;
  // stage ee2/ee3 into LDS, transposed + swizzled: dst[n*64+((kc^(n&15))<<2)+j]
  for (int idx = tid; idx < 4096; idx += THREADS) {
    int k = idx >> 6, n = idx & 63;
    int d = (n << 6) + ((((k >> 2) ^ (n & 15)) << 2)) + (k & 3);
    sW2[d] = P.ee2w[idx];
    sW3[d] = P.ee3w[idx];
  }
  float eb1 = P.ee1b[lane], eb2 = P.ee2b[lane], eb3 = P.ee3b[lane];
  __syncthreads();

  // ===== Phase A2: ee edge MLP over 496 pairs =====
  PAIR_PHASE(eb1, eb2, eb3);
  __syncthreads();

  // ===== Phase A3: ne node MLP -> z_cur in registers (2 rows/wave) =====
  float zci[2];
  {
    float nb1 = P.ne1b[lane];
    float nb2 = P.ne2b[lane];
    float nb3 = P.ne3b[cc];
    float nb4 = P.ne4b[cc];
    float o1[2] = {s1r[0] + nb1, s1r[1] + nb1};
    dense2<16>(sAgg + (i0 << 6), sAgg + (i1 << 6), P.ne1w + 512 * 64 + lane, 64, o1);
    pN0[lane] = frelu(o1[0]); pN1[lane] = frelu(o1[1]);
    float o2[2] = {nb2, nb2};
    dense2<16>(pN0, pN1, P.ne2w + lane, 64, o2);
    pM0[lane] = frelu(o2[0]); pM1[lane] = frelu(o2[1]);
    float o3[2] = {nb3, nb3};
    dense2<16>(pM0, pM1, P.ne3w + cc, 32, o3);
    pN0[cc] = frelu(o3[0]); pN1[cc] = frelu(o3[1]);   // dup writes, same value
    float o4[2] = {nb4, nb4};
    dense2<8>(pN0, pN1, P.ne4w + cc, 32, o4);
    zci[0] = (lane < 32) ? zb[(15 * NO + i0) * NEE + lane] : o4[0];
    zci[1] = (lane < 32) ? zb[(15 * NO + i1) * NEE + lane] : o4[1];
  }
  // stage le2/le3 pair weights (sW free: A2 done)
  for (int idx = tid; idx < 4096; idx += THREADS) {
    int k = idx >> 6, n = idx & 63;
    int d = (n << 6) + ((((k >> 2) ^ (n & 15)) << 2)) + (k & 3);
    sW2[d] = P.le2w[idx];
    sW3[d] = P.le3w[idx];
  }
  float gb1 = P.le1b[lane];
  float gb2 = P.le2b[lane];
  float gb3 = P.le3b[lane];
  float lb1 = P.lt1b[lane];
  float lb2 = P.lt2b[lane];
  float lb3 = P.lt3b[cc];
  float lb4 = P.lt4b[c16];
  float lb5 = P.lt5b[lane];
  // u/v for t=0 (bounce zc via scratch; overwrite scratch rows with u/v after)
  {
    pN0[lane] = zci[0]; pN1[lane] = zci[1];
    float ou[2] = {0, 0}, ov[2] = {0, 0};
    dense2<16>(pN0, pN1, P.le1w + lane, 64, ou);
    dense2<16>(pN0, pN1, P.le1w + 64 * 64 + lane, 64, ov);
    sU[(i0 << 6) + lane] = ou[0]; sU[(i1 << 6) + lane] = ou[1];
    sV[(i0 << 6) + lane] = ov[0]; sV[(i1 << 6) + lane] = ov[1];
    sAgg[(i0 << 6) + lane] = 0.f; sAgg[(i1 << 6) + lane] = 0.f;
  }
  float* outb = P.out + (size_t)b * P.tf * NO * NEE;
  __syncthreads();

  // ===== Phase B: t_future latent steps (2 barriers per step) =====
  for (int t = 0; t < P.tf; ++t) {
    PAIR_PHASE(gb1, gb2, gb3);
    __syncthreads();
    // lt node MLP (own rows; sU/sV rows used as scratch), state update, output
    pN0[lane] = zci[0]; pN1[lane] = zci[1];
    float o1[2] = {lb1, lb1};
    dense2<16>(pN0, pN1, P.lt1w + lane, 64, o1);
    dense2<16>(sAgg + (i0 << 6), sAgg + (i1 << 6), P.lt1w + 64 * 64 + lane, 64, o1);
    pM0[lane] = frelu(o1[0]); pM1[lane] = frelu(o1[1]);
    float o2[2] = {lb2, lb2};
    dense2<16>(pM0, pM1, P.lt2w + lane, 64, o2);
    pN0[lane] = frelu(o2[0]); pN1[lane] = frelu(o2[1]);
    float o3[2] = {lb3, lb3};
    dense2<16>(pN0, pN1, P.lt3w + cc, 32, o3);
    pM0[cc] = frelu(o3[0]); pM1[cc] = frelu(o3[1]);
    float o4[2] = {lb4, lb4};
    dense2<8>(pM0, pM1, P.lt4w + c16, 16, o4);
    pN0[c16] = frelu(o4[0]); pN1[c16] = frelu(o4[1]);
    float o5[2] = {lb5, lb5};
    dense2<4>(pN0, pN1, P.lt5w + lane, 64, o5);
    zci[0] += o5[0];
    zci[1] += o5[1];
    if (lane < 32) {
      outb[(t * NO + i0) * NEE + lane] = zci[0];
      outb[(t * NO + i1) * NEE + lane] = zci[1];
    }
    // u/v for next step (wasted on last iter; keeps work uniform)
    pN0[lane] = zci[0]; pN1[lane] = zci[1];
    float ou[2] = {0, 0}, ov[2] = {0, 0};
    dense2<16>(pN0, pN1, P.le1w + lane, 64, ou);
    dense2<16>(pN0, pN1, P.le1w + 64 * 64 + lane, 64, ov);
    sU[(i0 << 6) + lane] = ou[0]; sU[(i1 << 6) + lane] = ou[1];
    sV[(i0 << 6) + lane] = ov[0]; sV[(i1 << 6) + lane] = ov[1];
    sAgg[(i0 << 6) + lane] = 0.f; sAgg[(i1 << 6) + lane] = 0.f;
    __syncthreads();
  }
}

extern "C" void kernel_launch(void* const* d_in, const int* in_sizes, int n_in,
                              void* d_out, int out_size, void* d_ws, size_t ws_size,
                              hipStream_t stream) {
  (void)in_sizes; (void)n_in; (void)d_ws; (void)ws_size;
  Params P;
  int q = 0;
  P.z    = (fp)d_in[q++];
  P.ee1w = (fp)d_in[q++]; P.ee1b = (fp)d_in[q++];
  P.ee2w = (fp)d_in[q++]; P.ee2b = (fp)d_in[q++];
  P.ee3w = (fp)d_in[q++]; P.ee3b = (fp)d_in[q++];
  P.ne1w = (fp)d_in[q++]; P.ne1b = (fp)d_in[q++];
  P.ne2w = (fp)d_in[q++]; P.ne2b = (fp)d_in[q++];
  P.ne3w = (fp)d_in[q++]; P.ne3b = (fp)d_in[q++];
  P.ne4w = (fp)d_in[q++]; P.ne4b = (fp)d_in[q++];
  P.le1w = (fp)d_in[q++]; P.le1b = (fp)d_in[q++];
  P.le2w = (fp)d_in[q++]; P.le2b = (fp)d_in[q++];
  P.le3w = (fp)d_in[q++]; P.le3b = (fp)d_in[q++];
  P.lt1w = (fp)d_in[q++]; P.lt1b = (fp)d_in[q++];
  P.lt2w = (fp)d_in[q++]; P.lt2b = (fp)d_in[q++];
  P.lt3w = (fp)d_in[q++]; P.lt3b = (fp)d_in[q++];
  P.lt4w = (fp)d_in[q++]; P.lt4b = (fp)d_in[q++];
  P.lt5w = (fp)d_in[q++]; P.lt5b = (fp)d_in[q++];
  P.out = (float*)d_out;
  P.tf = out_size / (NB * NO * NEE);
  if (P.tf < 1) P.tf = 1;
  hipLaunchKernelGGL(rld_kernel, dim3(NB), dim3(THREADS), 0, stream, P);
}

// Round 9
// 1628.970 us; speedup vs baseline: 2.3889x; 2.3889x over previous
//
#include <hip/hip_runtime.h>

#define NB 256
#define NO 32
#define NEE 32
#define NT 16
#define THREADS 512

typedef const float* fp;

struct Params {
  fp z;
  fp ee1w, ee1b, ee2w, ee2b, ee3w, ee3b;
  fp ne1w, ne1b, ne2w, ne2b, ne3w, ne3b, ne4w, ne4b;
  fp le1w, le1b, le2w, le2b, le3w, le3b;
  fp lt1w, lt1b, lt2w, lt2b, lt3w, lt3b, lt4w, lt4b, lt5w, lt5b;
  float* out;
  int tf;
};

__device__ __forceinline__ float frelu(float x) { return x > 0.f ? x : 0.f; }

// LDS float offsets (single 16384-float block = exactly 64 KiB)
#define OFF_U   0       // 2048: u rows (A1: src-quarter low half)
#define OFF_V   2048    // 2048: v rows (A1: src-quarter high half)
#define OFF_AGG 4096    // 2048: edge aggregation
#define OFF_A   6144    // 4096: weight slot A
#define OFF_B   10240   // 4096: weight slot B
#define OFF_H   14336   // 2048: 8 waves x 4 x 64 h-bounce

// stage a 4096-float matrix global->LDS, natural layout (1024 f4, 2/thread)
__device__ __forceinline__ void stage4096(float* dst, const float* src, int tid) {
#pragma unroll
  for (int r = 0; r < 2; ++r) {
    int i4 = tid + r * THREADS;
    *(float4*)(dst + i4 * 4) = *(const float4*)(src + i4 * 4);
  }
}
// stage nf4 float4s, natural layout
__device__ __forceinline__ void stageN(float* dst, const float* src, int nf4, int tid) {
  for (int i4 = tid; i4 < nf4; i4 += THREADS)
    *(float4*)(dst + i4 * 4) = *(const float4*)(src + i4 * 4);
}
// stage [64][64] pair-weight matrix transposed+swizzled:
// element [k][o] -> dst[o*64 + ((k>>2 ^ (o&15))<<2) + (k&3)]  (b128-readable per lane)
__device__ __forceinline__ void stageSwz(float* dst, const float* src, int tid) {
#pragma unroll
  for (int r = 0; r < 2; ++r) {
    int i4 = tid + r * THREADS;          // 0..1023
    int k = i4 >> 4;
    int o4 = (i4 & 15) << 2;
    float4 v = *(const float4*)(src + k * 64 + o4);
    int kc = k >> 2, j = k & 3;
    dst[(o4 + 0) * 64 + ((kc ^ ((o4 + 0) & 15)) << 2) + j] = v.x;
    dst[(o4 + 1) * 64 + ((kc ^ ((o4 + 1) & 15)) << 2) + j] = v.y;
    dst[(o4 + 2) * 64 + ((kc ^ ((o4 + 2) & 15)) << 2) + j] = v.z;
    dst[(o4 + 3) * 64 + ((kc ^ ((o4 + 3) & 15)) << 2) + j] = v.w;
  }
}

// 4-row dense from LDS weights (natural [k][ldw], this lane's column `col`);
// x rows read as uniform float4 broadcasts; one weight read serves 4 rows.
template<int KC>
__device__ __forceinline__ void dense4L(const float* x0, const float* x1,
                                        const float* x2, const float* x3,
                                        const float* w, int ldw, int col, float o[4]) {
#pragma unroll
  for (int kc = 0; kc < KC; ++kc) {
    float w0 = w[(4 * kc + 0) * ldw + col];
    float w1 = w[(4 * kc + 1) * ldw + col];
    float w2 = w[(4 * kc + 2) * ldw + col];
    float w3 = w[(4 * kc + 3) * ldw + col];
    float4 a = *(const float4*)(x0 + 4 * kc);
    float4 b = *(const float4*)(x1 + 4 * kc);
    float4 c = *(const float4*)(x2 + 4 * kc);
    float4 d = *(const float4*)(x3 + 4 * kc);
    o[0] = fmaf(a.x, w0, o[0]); o[0] = fmaf(a.y, w1, o[0]); o[0] = fmaf(a.z, w2, o[0]); o[0] = fmaf(a.w, w3, o[0]);
    o[1] = fmaf(b.x, w0, o[1]); o[1] = fmaf(b.y, w1, o[1]); o[1] = fmaf(b.z, w2, o[1]); o[1] = fmaf(b.w, w3, o[1]);
    o[2] = fmaf(c.x, w0, o[2]); o[2] = fmaf(c.y, w1, o[2]); o[2] = fmaf(c.z, w2, o[2]); o[2] = fmaf(c.w, w3, o[2]);
    o[3] = fmaf(d.x, w0, o[3]); o[3] = fmaf(d.y, w1, o[3]); o[3] = fmaf(d.z, w2, o[3]); o[3] = fmaf(d.w, w3, o[3]);
  }
}

// Edge MLP over this wave's 64 pair slots (496 real + 16 dummy(0,0): +e/-e to the
// same address cancels). 4 pairs in flight; W2/W3 from swizzled LDS slots (one
// b128 weight read serves 4 pairs); pair indices by uniform scalar increment.
__device__ void pair_phase(float* lds, int wave, int lane, int swm,
                           float b1, float b2, float b3) {
  const float* sU = lds + OFF_U;
  const float* sV = lds + OFF_V;
  float* sAgg = lds + OFF_AGG;
  const float* wA = lds + OFF_A;
  const float* wB = lds + OFF_B;
  float* sH = lds + OFF_H + wave * 256;
  int pi = 0, rem = wave * 64;
  while (rem >= 31 - pi) { rem -= 31 - pi; ++pi; }   // unrank p0 (triu order)
  int pj = pi + 1 + rem;
  int pp = wave * 64;
  for (int qd = 0; qd < 16; ++qd) {
    int i4[4], j4[4];
#pragma unroll
    for (int q = 0; q < 4; ++q) {
      bool real = (pp < 496);
      i4[q] = real ? pi : 0;
      j4[q] = real ? pj : 0;
      if (real) { ++pj; if (pj == 32) { ++pi; pj = pi + 1; } }
      ++pp;
    }
#pragma unroll
    for (int q = 0; q < 4; ++q)
      sH[q * 64 + lane] = frelu(sU[i4[q] * 64 + lane] + sV[j4[q] * 64 + lane] + b1);
    float a[4][4];
#pragma unroll
    for (int q = 0; q < 4; ++q) { a[q][0] = b2; a[q][1] = 0.f; a[q][2] = 0.f; a[q][3] = 0.f; }
#pragma unroll
    for (int kc = 0; kc < 16; ++kc) {
      float4 w = *(const float4*)(wA + (lane << 6) + ((kc ^ swm) << 2));
#pragma unroll
      for (int q = 0; q < 4; ++q) {
        float4 x = *(const float4*)(sH + q * 64 + 4 * kc);
        a[q][0] = fmaf(x.x, w.x, a[q][0]); a[q][1] = fmaf(x.y, w.y, a[q][1]);
        a[q][2] = fmaf(x.z, w.z, a[q][2]); a[q][3] = fmaf(x.w, w.w, a[q][3]);
      }
    }
#pragma unroll
    for (int q = 0; q < 4; ++q)
      sH[q * 64 + lane] = frelu((a[q][0] + a[q][1]) + (a[q][2] + a[q][3]));
#pragma unroll
    for (int q = 0; q < 4; ++q) { a[q][0] = b3; a[q][1] = 0.f; a[q][2] = 0.f; a[q][3] = 0.f; }
#pragma unroll
    for (int kc = 0; kc < 16; ++kc) {
      float4 w = *(const float4*)(wB + (lane << 6) + ((kc ^ swm) << 2));
#pragma unroll
      for (int q = 0; q < 4; ++q) {
        float4 x = *(const float4*)(sH + q * 64 + 4 * kc);
        a[q][0] = fmaf(x.x, w.x, a[q][0]); a[q][1] = fmaf(x.y, w.y, a[q][1]);
        a[q][2] = fmaf(x.z, w.z, a[q][2]); a[q][3] = fmaf(x.w, w.w, a[q][3]);
      }
    }
#pragma unroll
    for (int q = 0; q < 4; ++q) {
      float e3 = (a[q][0] + a[q][1]) + (a[q][2] + a[q][3]);
      atomicAdd(&sAgg[i4[q] * 64 + lane],  e3);
      atomicAdd(&sAgg[j4[q] * 64 + lane], -e3);
    }
  }
}

__global__ __launch_bounds__(THREADS) void rld_kernel(Params P) {
  __shared__ float lds[16384];
  const int b = blockIdx.x;
  const int tid = (int)threadIdx.x;
  const int lane = tid & 63;
  const int wave = tid >> 6;
  const int cc = lane & 31;
  const int c16 = lane & 15;
  const int swm = lane & 15;

  float* sU = lds + OFF_U;
  float* sV = lds + OFF_V;
  float* sAgg = lds + OFF_AGG;
  float* slA = lds + OFF_A;
  float* slB = lds + OFF_B;
  float* sHme = lds + OFF_H + wave * 256;
  const int i0 = wave, i1 = wave + 8, i2 = wave + 16, i3 = wave + 24;
  const float* zb = P.z + (size_t)b * NT * NO * NEE;

  // ===== A1: src[32,512] @ {ee1a, ee1b, ne1a} via staged chunks =====
  float au[4] = {0, 0, 0, 0}, av[4] = {0, 0, 0, 0}, s1r[4] = {0, 0, 0, 0};
  for (int qq = 0; qq < 4; ++qq) {
    __syncthreads();                    // src region + slot readers done
    for (int idx = tid; idx < 4096; idx += THREADS) {  // src quarter -> [OFF_U,4096)
      int i = idx >> 7, kk = idx & 127;
      int k = qq * 128 + kk, t = k >> 5, e = k & 31;
      float v = zb[(t * NO + i) * NEE + e];
      if (t > 0) v -= zb[((t - 1) * NO + i) * NEE + e];
      lds[OFF_U + i * 128 + kk] = v;
    }
    for (int c = 0; c < 4; ++c) {
      __syncthreads();                  // publish src (c=0) / slot readers done
      {
        int r0 = qq * 128 + c * 32;
        int kk = tid >> 4, o4 = (tid & 15) << 2;   // 512 f4 per matrix, 1/thread
        *(float4*)(slA + kk * 64 + o4)        = *(const float4*)(P.ee1w + (r0 + kk) * 64 + o4);
        *(float4*)(slA + 2048 + kk * 64 + o4) = *(const float4*)(P.ee1w + (512 + r0 + kk) * 64 + o4);
        *(float4*)(slB + kk * 64 + o4)        = *(const float4*)(P.ne1w + (r0 + kk) * 64 + o4);
      }
      __syncthreads();
      const float* x0 = lds + OFF_U + i0 * 128 + c * 32;
      const float* x1 = lds + OFF_U + i1 * 128 + c * 32;
      const float* x2 = lds + OFF_U + i2 * 128 + c * 32;
      const float* x3 = lds + OFF_U + i3 * 128 + c * 32;
      dense4L<8>(x0, x1, x2, x3, slA, 64, lane, au);
      dense4L<8>(x0, x1, x2, x3, slA + 2048, 64, lane, av);
      dense4L<8>(x0, x1, x2, x3, slB, 64, lane, s1r);
    }
  }
  __syncthreads();                      // all src/slot reads done
  sU[i0 * 64 + lane] = au[0]; sU[i1 * 64 + lane] = au[1];
  sU[i2 * 64 + lane] = au[2]; sU[i3 * 64 + lane] = au[3];
  sV[i0 * 64 + lane] = av[0]; sV[i1 * 64 + lane] = av[1];
  sV[i2 * 64 + lane] = av[2]; sV[i3 * 64 + lane] = av[3];
  sAgg[i0 * 64 + lane] = 0.f; sAgg[i1 * 64 + lane] = 0.f;
  sAgg[i2 * 64 + lane] = 0.f; sAgg[i3 * 64 + lane] = 0.f;
  stageSwz(slA, P.ee2w, tid);
  stageSwz(slB, P.ee3w, tid);
  float eb1 = P.ee1b[lane], eb2 = P.ee2b[lane], eb3 = P.ee3b[lane];
  __syncthreads();

  // ===== A2: ee edge MLP =====
  pair_phase(lds, wave, lane, swm, eb1, eb2, eb3);
  __syncthreads();

  // ===== A3: ne node MLP -> zci[4] =====
  float zci[4];
  {
    float nb1 = P.ne1b[lane], nb2 = P.ne2b[lane];
    float nb3 = P.ne3b[cc],   nb4 = P.ne4b[cc];
    stage4096(slA, P.ne1w + 512 * 64, tid);   // ne1 agg-half
    stage4096(slB, P.ne2w, tid);
    __syncthreads();
    float o1[4] = {s1r[0] + nb1, s1r[1] + nb1, s1r[2] + nb1, s1r[3] + nb1};
    dense4L<16>(sAgg + i0 * 64, sAgg + i1 * 64, sAgg + i2 * 64, sAgg + i3 * 64, slA, 64, lane, o1);
    sU[i0 * 64 + lane] = frelu(o1[0]); sU[i1 * 64 + lane] = frelu(o1[1]);
    sU[i2 * 64 + lane] = frelu(o1[2]); sU[i3 * 64 + lane] = frelu(o1[3]);
    float o2[4] = {nb2, nb2, nb2, nb2};
    dense4L<16>(sU + i0 * 64, sU + i1 * 64, sU + i2 * 64, sU + i3 * 64, slB, 64, lane, o2);
    sV[i0 * 64 + lane] = frelu(o2[0]); sV[i1 * 64 + lane] = frelu(o2[1]);
    sV[i2 * 64 + lane] = frelu(o2[2]); sV[i3 * 64 + lane] = frelu(o2[3]);
    __syncthreads();                    // ne1/ne2 slot readers done
    stageN(slA, P.ne3w, 512, tid);      // 64x32
    stageN(slA + 2048, P.ne4w, 256, tid); // 32x32
    __syncthreads();
    float o3[4] = {nb3, nb3, nb3, nb3};
    dense4L<16>(sV + i0 * 64, sV + i1 * 64, sV + i2 * 64, sV + i3 * 64, slA, 32, cc, o3);
    sU[i0 * 64 + cc] = frelu(o3[0]); sU[i1 * 64 + cc] = frelu(o3[1]);
    sU[i2 * 64 + cc] = frelu(o3[2]); sU[i3 * 64 + cc] = frelu(o3[3]);
    float o4[4] = {nb4, nb4, nb4, nb4};
    dense4L<8>(sU + i0 * 64, sU + i1 * 64, sU + i2 * 64, sU + i3 * 64, slA + 2048, 32, cc, o4);
    zci[0] = (lane < 32) ? zb[(15 * NO + i0) * NEE + lane] : o4[0];
    zci[1] = (lane < 32) ? zb[(15 * NO + i1) * NEE + lane] : o4[1];
    zci[2] = (lane < 32) ? zb[(15 * NO + i2) * NEE + lane] : o4[2];
    zci[3] = (lane < 32) ? zb[(15 * NO + i3) * NEE + lane] : o4[3];
  }

  float gb1 = P.le1b[lane], gb2 = P.le2b[lane], gb3 = P.le3b[lane];
  float lb1 = P.lt1b[lane], lb2 = P.lt2b[lane];
  float lb3 = P.lt3b[cc],  lb4 = P.lt4b[c16], lb5 = P.lt5b[lane];
  float* outb = P.out + (size_t)b * P.tf * NO * NEE;

  // ===== Phase B: t_future steps, rotating LDS weight slots (8 barriers/step) =====
  for (int t = 0; t < P.tf; ++t) {
    __syncthreads();                    // prior slot readers done
    stage4096(slA, P.le1w, tid);        // le1 rows 0..63  (u)
    stage4096(slB, P.le1w + 4096, tid); // le1 rows 64..127 (v)
    __syncthreads();
    sHme[lane] = zci[0]; sHme[64 + lane] = zci[1];
    sHme[128 + lane] = zci[2]; sHme[192 + lane] = zci[3];
    float ou[4] = {0, 0, 0, 0}, ov[4] = {0, 0, 0, 0};
    dense4L<16>(sHme, sHme + 64, sHme + 128, sHme + 192, slA, 64, lane, ou);
    dense4L<16>(sHme, sHme + 64, sHme + 128, sHme + 192, slB, 64, lane, ov);
    sU[i0 * 64 + lane] = ou[0]; sU[i1 * 64 + lane] = ou[1];
    sU[i2 * 64 + lane] = ou[2]; sU[i3 * 64 + lane] = ou[3];
    sV[i0 * 64 + lane] = ov[0]; sV[i1 * 64 + lane] = ov[1];
    sV[i2 * 64 + lane] = ov[2]; sV[i3 * 64 + lane] = ov[3];
    sAgg[i0 * 64 + lane] = 0.f; sAgg[i1 * 64 + lane] = 0.f;
    sAgg[i2 * 64 + lane] = 0.f; sAgg[i3 * 64 + lane] = 0.f;
    __syncthreads();                    // u/v/agg published; le1 readers done
    stageSwz(slA, P.le2w, tid);
    stageSwz(slB, P.le3w, tid);
    __syncthreads();
    pair_phase(lds, wave, lane, swm, gb1, gb2, gb3);
    __syncthreads();
    stage4096(slA, P.lt1w, tid);        // lt1 zc-half
    stage4096(slB, P.lt1w + 4096, tid); // lt1 agg-half
    __syncthreads();
    sHme[lane] = zci[0]; sHme[64 + lane] = zci[1];
    sHme[128 + lane] = zci[2]; sHme[192 + lane] = zci[3];
    float o1[4] = {lb1, lb1, lb1, lb1};
    dense4L<16>(sHme, sHme + 64, sHme + 128, sHme + 192, slA, 64, lane, o1);
    dense4L<16>(sAgg + i0 * 64, sAgg + i1 * 64, sAgg + i2 * 64, sAgg + i3 * 64, slB, 64, lane, o1);
    sU[i0 * 64 + lane] = frelu(o1[0]); sU[i1 * 64 + lane] = frelu(o1[1]);
    sU[i2 * 64 + lane] = frelu(o1[2]); sU[i3 * 64 + lane] = frelu(o1[3]);
    __syncthreads();                    // lt1 readers done
    stage4096(slA, P.lt2w, tid);
    stageN(slB, P.lt3w, 512, tid);
    stageN(slB + 2048, P.lt4w, 128, tid);
    stageN(slB + 2560, P.lt5w, 256, tid);
    __syncthreads();
    float o2[4] = {lb2, lb2, lb2, lb2};
    dense4L<16>(sU + i0 * 64, sU + i1 * 64, sU + i2 * 64, sU + i3 * 64, slA, 64, lane, o2);
    sV[i0 * 64 + lane] = frelu(o2[0]); sV[i1 * 64 + lane] = frelu(o2[1]);
    sV[i2 * 64 + lane] = frelu(o2[2]); sV[i3 * 64 + lane] = frelu(o2[3]);
    float o3[4] = {lb3, lb3, lb3, lb3};
    dense4L<16>(sV + i0 * 64, sV + i1 * 64, sV + i2 * 64, sV + i3 * 64, slB, 32, cc, o3);
    sU[i0 * 64 + cc] = frelu(o3[0]); sU[i1 * 64 + cc] = frelu(o3[1]);
    sU[i2 * 64 + cc] = frelu(o3[2]); sU[i3 * 64 + cc] = frelu(o3[3]);
    float o4[4] = {lb4, lb4, lb4, lb4};
    dense4L<8>(sU + i0 * 64, sU + i1 * 64, sU + i2 * 64, sU + i3 * 64, slB + 2048, 16, c16, o4);
    sV[i0 * 64 + c16] = frelu(o4[0]); sV[i1 * 64 + c16] = frelu(o4[1]);
    sV[i2 * 64 + c16] = frelu(o4[2]); sV[i3 * 64 + c16] = frelu(o4[3]);
    float o5[4] = {lb5, lb5, lb5, lb5};
    dense4L<4>(sV + i0 * 64, sV + i1 * 64, sV + i2 * 64, sV + i3 * 64, slB + 2560, 64, lane, o5);
    zci[0] += o5[0]; zci[1] += o5[1]; zci[2] += o5[2]; zci[3] += o5[3];
    if (lane < 32) {
      outb[(t * NO + i0) * NEE + lane] = zci[0];
      outb[(t * NO + i1) * NEE + lane] = zci[1];
      outb[(t * NO + i2) * NEE + lane] = zci[2];
      outb[(t * NO + i3) * NEE + lane] = zci[3];
    }
  }
}

extern "C" void kernel_launch(void* const* d_in, const int* in_sizes, int n_in,
                              void* d_out, int out_size, void* d_ws, size_t ws_size,
                              hipStream_t stream) {
  (void)in_sizes; (void)n_in; (void)d_ws; (void)ws_size;
  Params P;
  int q = 0;
  P.z    = (fp)d_in[q++];
  P.ee1w = (fp)d_in[q++]; P.ee1b = (fp)d_in[q++];
  P.ee2w = (fp)d_in[q++]; P.ee2b = (fp)d_in[q++];
  P.ee3w = (fp)d_in[q++]; P.ee3b = (fp)d_in[q++];
  P.ne1w = (fp)d_in[q++]; P.ne1b = (fp)d_in[q++];
  P.ne2w = (fp)d_in[q++]; P.ne2b = (fp)d_in[q++];
  P.ne3w = (fp)d_in[q++]; P.ne3b = (fp)d_in[q++];
  P.ne4w = (fp)d_in[q++]; P.ne4b = (fp)d_in[q++];
  P.le1w = (fp)d_in[q++]; P.le1b = (fp)d_in[q++];
  P.le2w = (fp)d_in[q++]; P.le2b = (fp)d_in[q++];
  P.le3w = (fp)d_in[q++]; P.le3b = (fp)d_in[q++];
  P.lt1w = (fp)d_in[q++]; P.lt1b = (fp)d_in[q++];
  P.lt2w = (fp)d_in[q++]; P.lt2b = (fp)d_in[q++];
  P.lt3w = (fp)d_in[q++]; P.lt3b = (fp)d_in[q++];
  P.lt4w = (fp)d_in[q++]; P.lt4b = (fp)d_in[q++];
  P.lt5w = (fp)d_in[q++]; P.lt5b = (fp)d_in[q++];
  P.out = (float*)d_out;
  P.tf = out_size / (NB * NO * NEE);
  if (P.tf < 1) P.tf = 1;
  hipLaunchKernelGGL(rld_kernel, dim3(NB), dim3(THREADS), 0, stream, P);
}